// Round 3
// baseline (434.915 us; speedup 1.0000x reference)
//
#include <hip/hip_runtime.h>
#include <stdint.h>

// Exact fp32 reproduction of the numpy reference requires no FMA contraction
// and identical association order everywhere below.
#pragma clang fp contract(off)

#define B_    4
#define NV_   6890
#define NF_   27552     // 2*13776
#define IMG_  128
#define UV_   256
#define NPIX  (IMG_*IMG_)

#define TS_     8                 // tile edge in pixels
#define TPB_    (IMG_/TS_)        // 16 tiles per row/col
#define NTILE_  (TPB_*TPB_)       // 256 tiles per batch
#define NBIN_   (B_*NTILE_)       // 1024 bins
#define LIST_CAP (2*1024*1024)    // entries (8 MB); measured need ~1.2M

// ---------------------------------------------------------------- projection
__global__ void __launch_bounds__(256) project_k(
    const float* __restrict__ cam, const float* __restrict__ verts,
    float* __restrict__ vp) {
  int idx = blockIdx.x * 256 + threadIdx.x;
  if (idx >= B_ * NV_) return;
  int b = idx / NV_;
  float c0 = cam[b * 3 + 0], c1 = cam[b * 3 + 1], c2 = cam[b * 3 + 2];
  float tz = 500.0f / (64.0f * c0);                  // FLENGTH/(p*cam0), p=64
  const float* src = verts + (size_t)idx * 3;
  float* dst = vp + (size_t)idx * 3;
  dst[0] = c0 * (src[0] + c1);
  dst[1] = c0 * (src[1] + c2);
  dst[2] = src[2] + tz;
}

// ------------------------------------------------------------------- binning
// Backface cull (area_c < -1e-3, bit-safe bound proven in R1) + bbox(+-1px)
// -> range of overlapped 8x8 tiles. Also outputs z16 = top 16 bits of the
// face's exact zmin (truncation toward zero == downward for positive z, so
// decode(z16) <= zmin: conservative for the hi-z prune).
__device__ __forceinline__ int face_tiles(
    const float* __restrict__ vp, const int* __restrict__ faces, int b, int f,
    int& tx0, int& tx1, int& ty0, int& ty1, unsigned& z16) {
  int ia = faces[f * 3 + 0], ib = faces[f * 3 + 1], ic = faces[f * 3 + 2];
  const float* vb = vp + (size_t)b * NV_ * 3;
  float x0 = vb[ia * 3 + 0], y0 = vb[ia * 3 + 1];
  float x1 = vb[ib * 3 + 0], y1 = vb[ib * 3 + 1];
  float x2 = vb[ic * 3 + 0], y2 = vb[ic * 3 + 1];
  float area_c = (x1 - x0) * (y2 - y0) - (y1 - y0) * (x2 - x0);
  if (area_c < -1e-3f) return 0;
  float xmn = fminf(x0, fminf(x1, x2)), xmx = fmaxf(x0, fmaxf(x1, x2));
  float ymn = fminf(y0, fminf(y1, y2)), ymx = fmaxf(y0, fmaxf(y1, y2));
  int jlo = (int)floorf((xmn + 1.0f) * 64.0f - 0.5f) - 1;
  int jhi = (int)ceilf ((xmx + 1.0f) * 64.0f - 0.5f) + 1;
  int ilo = (int)floorf((1.0f - ymx) * 64.0f - 0.5f) - 1;
  int ihi = (int)ceilf ((1.0f - ymn) * 64.0f - 0.5f) + 1;
  if (jhi < 0 || ihi < 0 || jlo > IMG_ - 1 || ilo > IMG_ - 1) return 0;
  jlo = max(jlo, 0); ilo = max(ilo, 0);
  jhi = min(jhi, IMG_ - 1); ihi = min(ihi, IMG_ - 1);
  tx0 = jlo >> 3; tx1 = jhi >> 3; ty0 = ilo >> 3; ty1 = ihi >> 3;
  float z0 = vb[ia * 3 + 2], z1 = vb[ib * 3 + 2], z2 = vb[ic * 3 + 2];
  z16 = __float_as_uint(fminf(z0, fminf(z1, z2))) >> 16;
  return 1;
}

// Block-local LDS count aggregation (R5-validated). rects now carries
// z16 in the high half (0xFFFF = invalid; real z16 ~ 0x40C0..0x4140).
__global__ void __launch_bounds__(256) bin_count_k(
    const float* __restrict__ vp, const int* __restrict__ faces,
    int* __restrict__ cnt, int* __restrict__ rects) {
  __shared__ int scnt[NTILE_];
  int f = blockIdx.x * 256 + threadIdx.x;
  int b = blockIdx.y;
  scnt[threadIdx.x] = 0;
  __syncthreads();
  int tx0, tx1, ty0, ty1;
  unsigned z16 = 0;
  int valid =
      (f < NF_) ? face_tiles(vp, faces, b, f, tx0, tx1, ty0, ty1, z16) : 0;
  if (f < NF_)
    rects[(size_t)b * NF_ + f] =
        valid ? (int)((z16 << 16) | (unsigned)(tx0 | (tx1 << 4) | (ty0 << 8) |
                                               (ty1 << 12)))
              : (int)0xFFFF0000u;
  if (valid)
    for (int ty = ty0; ty <= ty1; ++ty)
      for (int tx = tx0; tx <= tx1; ++tx)
        atomicAdd(&scnt[ty * TPB_ + tx], 1);
  __syncthreads();
  int t = threadIdx.x;
  int v = scnt[t];
  if (v > 0) atomicAdd(&cnt[b * NTILE_ + t], v);
}

// Scan bin counts -> offsets (work-chunk list no longer needed: raster is
// one persistent block per bin).
__global__ void __launch_bounds__(1024) scan_k(
    const int* __restrict__ cnt, int* __restrict__ off, int* __restrict__ cur) {
  __shared__ int sm[NBIN_];
  int t = threadIdx.x;
  int v = cnt[t];
  sm[t] = v;
  __syncthreads();
  for (int d = 1; d < NBIN_; d <<= 1) {
    int u = (t >= d) ? sm[t - d] : 0;
    __syncthreads();
    sm[t] += u;
    __syncthreads();
  }
  int o = sm[t] - v;
  off[t] = o;
  cur[t] = o;
}

// Block-local fill (R5-validated). List entry packs (z16 << 15) | fid:
// fid < 27552 fits 15 bits; z16 top bit is 0 (z positive) -> int-safe.
__global__ void __launch_bounds__(256) bin_fill_k(
    const int* __restrict__ rects, int* __restrict__ cur,
    int* __restrict__ list) {
  __shared__ int scnt[NTILE_];
  __shared__ int sbase[NTILE_];
  int f = blockIdx.x * 256 + threadIdx.x;
  int b = blockIdx.y;
  scnt[threadIdx.x] = 0;
  __syncthreads();
  unsigned rv =
      (f < NF_) ? (unsigned)rects[(size_t)b * NF_ + f] : 0xFFFF0000u;
  unsigned hi = rv >> 16;
  int valid = (hi != 0xFFFFu);
  int tx0 = rv & 15, tx1 = (rv >> 4) & 15;
  int ty0 = (rv >> 8) & 15, ty1 = (rv >> 12) & 15;
  if (valid)
    for (int ty = ty0; ty <= ty1; ++ty)
      for (int tx = tx0; tx <= tx1; ++tx)
        atomicAdd(&scnt[ty * TPB_ + tx], 1);
  __syncthreads();
  int t = threadIdx.x;
  int v = scnt[t];
  if (v > 0) sbase[t] = atomicAdd(&cur[b * NTILE_ + t], v);
  __syncthreads();
  scnt[t] = 0;            // reuse as per-bin rank counter
  __syncthreads();
  if (valid) {
    int ev = (int)((hi << 15) | (unsigned)f);
    for (int ty = ty0; ty <= ty1; ++ty)
      for (int tx = tx0; tx <= tx1; ++tx) {
        int bin = ty * TPB_ + tx;
        int r = atomicAdd(&scnt[bin], 1);
        int slot = sbase[bin] + r;
        if (slot < LIST_CAP) list[slot] = ev;
      }
  }
}

// ---------------------------------------------------------------- rasterizer
// R9: one persistent 256-thread block per bin; each of the 4 waves strides
// the bin's face list in 64-entry slices, fully independently (no barriers
// until the final merge). Pixels partition exactly by bin -> plain store,
// no zkey memset, no atomics, no seeds.
//
// Hi-z prune: skip a face when its packed zmin code exceeds thr_code =
// top16(wavemax(kbz)*1.01). kbz is the EXACT z of a candidate this wave
// already holds in kb; exact zp >= zmin*(1-~1e-6) (fp harmonic interp),
// and code truncation is downward, so the 1% margin makes the skip strict:
// the face loses everywhere in the tile. Survivors (ballot-compacted) run
// the R6/R2-validated approx-zpa pass (rel err <~2e-5 vs 1.001 margins):
// prefix near-minima + window-uncertain faces go to qmask; the tail
// re-filters against min(win, kbz)*1.001 and runs the exact reference
// divide chain only for survivors. Any face skipped anywhere provably has
// exact zp strictly above an exact candidate that reaches kb.
__global__ void __launch_bounds__(256) raster_k(
    const float* __restrict__ vp, const int* __restrict__ faces,
    const int* __restrict__ list, const int* __restrict__ cnt,
    const int* __restrict__ off, unsigned long long* __restrict__ zkey) {
  __shared__ float4 fd[4][5][64];   // [wave][field][slot]; wave-private
  __shared__ unsigned long long mg[4][64];
  int bin = blockIdx.x;
  int b = bin >> 8;
  int t = bin & 255;
  int tyT = t >> 4, txT = t & 15;
  int ws = threadIdx.x >> 6, lane = threadIdx.x & 63;
  int pi = tyT * TS_ + (lane >> 3);
  int pj = txT * TS_ + (lane & 7);
  // exact: (2j+1)/128-1 and 1-(2i+1)/128 are multiples of 2^-7 in [-1,1]
  float px = fmaf((float)pj, 0.015625f, -0.9921875f);
  float py = fmaf((float)pi, -0.015625f, 0.9921875f);

  int n = cnt[bin];
  int base = off[bin];

  unsigned long long kb = ~0ull;
  unsigned kbz_u = 0x7F800000u;     // exact z of current best (+inf if none)
  unsigned thr_code = 0xFFFFu;      // hi-z prune code (max -> no prune)
  const float* vb = vp + (size_t)b * NV_ * 3;

  for (int seg = ws * 64; seg < n; seg += 256) {
    int mw = min(n - seg, 64);
    // ---- cheap zmin prefilter on the packed list word (coalesced)
    bool live = false;
    int fid = 0;
    if (lane < mw) {
      unsigned e = (unsigned)list[base + seg + lane];
      live = ((e >> 15) <= thr_code);
      fid = (int)(e & 0x7FFFu);
    }
    unsigned long long bal = __ballot(live);
    if (bal == 0ull) continue;
    int nsurv = (int)__popcll(bal);
    int rank = (int)__popcll(bal & ((1ull << lane) - 1ull));
    if (live) {
      int ia = faces[fid * 3 + 0], ib = faces[fid * 3 + 1],
          ic = faces[fid * 3 + 2];
      float X0 = vb[ia * 3 + 0], Y0 = vb[ia * 3 + 1], Z0 = vb[ia * 3 + 2];
      float X1 = vb[ib * 3 + 0], Y1 = vb[ib * 3 + 1], Z1 = vb[ib * 3 + 2];
      float X2 = vb[ic * 3 + 0], Y2 = vb[ic * 3 + 1], Z2 = vb[ic * 3 + 2];
      fd[ws][0][rank] = make_float4(X2 - X1, Y2 - Y1, X1, Y1);   // d21, v1
      fd[ws][1][rank] = make_float4(X0 - X2, Y0 - Y2, X2, Y2);   // d02, v2
      fd[ws][2][rank] = make_float4(X1 - X0, Y1 - Y0, X0, Y0);   // d10, v0
      fd[ws][3][rank] = make_float4(Z0, Z1, Z2, __int_as_float(fid));
      fd[ws][4][rank] =
          make_float4(Z1 * Z2, Z0 * Z2, Z0 * Z1, Z0 * Z1 * Z2);
    }
    // wave-private LDS: in-order per-wave DS pipe, no barrier needed.

    // ---- branchless approx pass with prefix-near-min qmask
    unsigned win_u = 0x7F800000u;
    unsigned long long qm = 0ull;
    for (int q = 0; q < nsurv; ++q) {
      float4 A = fd[ws][0][q];
      float4 Bv = fd[ws][1][q];
      float4 Cv = fd[ws][2][q];
      float w0 = A.x * (py - A.w) - A.y * (px - A.z);
      float w1 = Bv.x * (py - Bv.w) - Bv.y * (px - Bv.z);
      float w2 = Cv.x * (py - Cv.w) - Cv.y * (px - Cv.z);
      float area = (w0 + w1) + w2;
      float mn = fminf(w0, fminf(w1, w2));
      bool pred = (area > 0.0f) && !(mn < 0.0f);
      if (!__any(pred)) continue;
      float4 P = fd[ws][4][q];
      float num = (w0 * P.x + w1 * P.y) + w2 * P.z;
      float zpa = (area * P.w) * __builtin_amdgcn_rcpf(num);
      unsigned cu = win_u < kbz_u ? win_u : kbz_u;
      float thrq = __uint_as_float(cu) * 1.001f;
      bool amb = pred && (!(zpa > thrq) ||
                          (zpa > 0.09989f && zpa < 0.10011f) ||
                          (zpa > 24.9724f && zpa < 25.0276f));
      if (amb) qm |= 1ull << q;
      bool ok = pred && (zpa > 0.1001f) && (zpa < 24.975f);
      unsigned zb = __float_as_uint(zpa);
      if (ok && zb < win_u) win_u = zb;
    }

    // ---- exact tail: re-filter vs final threshold, then reference chain
    while (__any(qm != 0ull)) {
      if (qm != 0ull) {
        int q = __ffsll(qm) - 1;
        qm &= qm - 1ull;
        float4 A = fd[ws][0][q];
        float4 Bv = fd[ws][1][q];
        float4 Cv = fd[ws][2][q];
        float w0 = A.x * (py - A.w) - A.y * (px - A.z);
        float w1 = Bv.x * (py - Bv.w) - Bv.y * (px - Bv.z);
        float w2 = Cv.x * (py - Cv.w) - Cv.y * (px - Cv.z);
        float area = (w0 + w1) + w2;
        float4 P = fd[ws][4][q];
        float num = (w0 * P.x + w1 * P.y) + w2 * P.z;
        float zpa = (area * P.w) * __builtin_amdgcn_rcpf(num);
        unsigned cu = win_u < kbz_u ? win_u : kbz_u;
        float thrf = __uint_as_float(cu) * 1.001f;
        if (!(zpa > thrf) ||
            (zpa > 0.09989f && zpa < 0.10011f) ||
            (zpa > 24.9724f && zpa < 25.0276f)) {
          float4 Z = fd[ws][3][q];
          float b0 = w0 / area, b1 = w1 / area, b2 = w2 / area;
          float invz = (b0 / Z.x + b1 / Z.y) + b2 / Z.z;
          float zp = 1.0f / (invz == 0.0f ? 1.0f : invz);
          if (zp > 0.1f && zp < 25.0f) {
            unsigned long long key =
                ((unsigned long long)__float_as_uint(zp) << 32) |
                (unsigned int)__float_as_int(Z.w);
            if (key < kb) {
              kb = key;
              kbz_u = (unsigned)(kb >> 32);
            }
          }
        }
      }
    }

    // ---- refresh hi-z prune threshold: wavemax of exact kbz, +1% margin
    unsigned mx = kbz_u;
    for (int j = 1; j < 64; j <<= 1) {
      unsigned o = (unsigned)__shfl_xor((int)mx, j, 64);
      mx = o > mx ? o : mx;
    }
    thr_code = __float_as_uint(__uint_as_float(mx) * 1.01f) >> 16;
  }

  mg[ws][lane] = kb;
  __syncthreads();
  if (ws == 0) {
    unsigned long long k0 = mg[0][lane];
    unsigned long long k1 = mg[1][lane];
    unsigned long long k2 = mg[2][lane];
    unsigned long long k3 = mg[3][lane];
    k0 = k1 < k0 ? k1 : k0;
    k2 = k3 < k2 ? k3 : k2;
    k0 = k2 < k0 ? k2 : k0;
    // pixels partition by bin: exactly one writer -> plain store (covers
    // the no-memset init too; ~0 == "empty" sentinel for shade_k).
    zkey[(size_t)b * NPIX + pi * IMG_ + pj] = k0;
  }
}

// ------------------------------------------------------------------- shading
#define TAP(ty, tx, wexpr)                                                   \
  {                                                                          \
    int ty_ = (ty), tx_ = (tx);                                              \
    float w_ = (wexpr);                                                      \
    float valid_ =                                                           \
        (tx_ >= 0 && tx_ < UV_ && ty_ >= 0 && ty_ < UV_) ? 1.0f : 0.0f;      \
    float wv_ = w_ * valid_;                                                 \
    int cy_ = min(max(ty_, 0), UV_ - 1), cx_ = min(max(tx_, 0), UV_ - 1);    \
    int o_ = cy_ * UV_ + cx_;                                                \
    cr = cr + img[o_] * wv_;                                                 \
    cg = cg + img[UV_ * UV_ + o_] * wv_;                                     \
    cb = cb + img[2 * UV_ * UV_ + o_] * wv_;                                 \
  }

__global__ void __launch_bounds__(256) shade_k(
    const float* __restrict__ vp, const int* __restrict__ faces,
    const float* __restrict__ uv, const float* __restrict__ samp,
    const unsigned long long* __restrict__ zkey, float* __restrict__ out) {
  int idx = blockIdx.x * 256 + threadIdx.x;
  if (idx >= B_ * NPIX) return;
  int b = idx / NPIX;
  int p = idx - b * NPIX;
  int ii = p / IMG_;
  int jj = p - ii * IMG_;

  unsigned long long key = zkey[idx];
  float cr = 0.0f, cg = 0.0f, cb = 0.0f;
  if (key != 0xFFFFFFFFFFFFFFFFull) {
    int f = (int)(key & 0xFFFFFFFFull);
    int ia = faces[f * 3 + 0], ib = faces[f * 3 + 1], ic = faces[f * 3 + 2];
    const float* vb = vp + (size_t)b * NV_ * 3;
    float x0 = vb[ia * 3 + 0], y0 = vb[ia * 3 + 1];
    float x1 = vb[ib * 3 + 0], y1 = vb[ib * 3 + 1];
    float x2 = vb[ic * 3 + 0], y2 = vb[ic * 3 + 1];
    float px = (float)(2 * jj + 1) / 128.0f - 1.0f;
    float py = 1.0f - (float)(2 * ii + 1) / 128.0f;
    float w0 = (x2 - x1) * (py - y1) - (y2 - y1) * (px - x1);
    float w1 = (x0 - x2) * (py - y2) - (y0 - y2) * (px - x2);
    float w2 = (x1 - x0) * (py - y0) - (y1 - y0) * (px - x0);
    float area = (w0 + w1) + w2;
    float s = (area == 0.0f) ? 1.0f : area;
    float b0 = w0 / s, b1 = w1 / s;
    int t0 = min(max((int)floorf(b0 * 3.0f), 0), 2);
    int t1 = min(max((int)floorf(b1 * 3.0f), 0), 2);

    // lazy texture fetch: textures[b,f,t0,t1,*,c] == bilinear(uv_imgs[b],
    // sampler[f, t0*3+t1]); lighting multiplier is exactly 1.0 -> skipped.
    const float* g = samp + ((size_t)f * 9 + (size_t)(t0 * 3 + t1)) * 2;
    float gx = g[0], gy = g[1];
    float x = (gx + 1.0f) * 128.0f - 0.5f;   // (g+1)*(W*0.5)-0.5, W=256
    float y = (gy + 1.0f) * 128.0f - 0.5f;
    float x0f = floorf(x), y0f = floorf(y);
    float wx = x - x0f, wy = y - y0f;
    int xi = (int)x0f, yi = (int)y0f;
    float omwx = 1.0f - wx, omwy = 1.0f - wy;
    const float* img = uv + (size_t)b * 3 * UV_ * UV_;
    // reference accumulation order: (y0,x0)+(y0,x0+1)+(y0+1,x0)+(y0+1,x0+1)
    TAP(yi,     xi,     omwx * omwy)
    TAP(yi,     xi + 1, wx * omwy)
    TAP(yi + 1, xi,     omwx * wy)
    TAP(yi + 1, xi + 1, wx * wy)
  }
  out[((size_t)b * 3 + 0) * NPIX + p] = cr;
  out[((size_t)b * 3 + 1) * NPIX + p] = cg;
  out[((size_t)b * 3 + 2) * NPIX + p] = cb;
}

// ------------------------------------------------------------------- launch
extern "C" void kernel_launch(void* const* d_in, const int* in_sizes, int n_in,
                              void* d_out, int out_size, void* d_ws,
                              size_t ws_size, hipStream_t stream) {
  const float* cam   = (const float*)d_in[0];
  const float* verts = (const float*)d_in[1];
  const float* uv    = (const float*)d_in[2];
  const float* samp  = (const float*)d_in[3];
  const int*   faces = (const int*)d_in[4];

  char* ws = (char*)d_ws;
  size_t o = 0;
  unsigned long long* zkey = (unsigned long long*)(ws + o);
  o += (size_t)B_ * NPIX * 8;                                   // 512 KB
  float* vp = (float*)(ws + o);
  o += ((size_t)B_ * NV_ * 3 * 4 + 1023) & ~1023ull;            // ~331 KB
  int* cnt   = (int*)(ws + o); o += NBIN_ * 4;
  int* offs  = (int*)(ws + o); o += NBIN_ * 4;
  int* cur   = (int*)(ws + o); o += NBIN_ * 4;
  int* rects = (int*)(ws + o); o += (size_t)B_ * NF_ * 4;       // 440 KB
  int* list  = (int*)(ws + o);                                  // 8 MB

  hipMemsetAsync(cnt, 0, NBIN_ * 4, stream);
  project_k<<<(B_ * NV_ + 255) / 256, 256, 0, stream>>>(cam, verts, vp);
  dim3 bgrid((NF_ + 255) / 256, B_);
  bin_count_k<<<bgrid, 256, 0, stream>>>(vp, faces, cnt, rects);
  scan_k<<<1, NBIN_, 0, stream>>>(cnt, offs, cur);
  bin_fill_k<<<bgrid, 256, 0, stream>>>(rects, cur, list);
  raster_k<<<NBIN_, 256, 0, stream>>>(vp, faces, list, cnt, offs, zkey);
  shade_k<<<(B_ * NPIX + 255) / 256, 256, 0, stream>>>(vp, faces, uv, samp,
                                                       zkey, (float*)d_out);
}

// Round 4
// 182.378 us; speedup vs baseline: 2.3847x; 2.3847x over previous
//
#include <hip/hip_runtime.h>
#include <stdint.h>

// Exact fp32 reproduction of the numpy reference requires no FMA contraction
// and identical association order everywhere below.
#pragma clang fp contract(off)

#define B_    4
#define NV_   6890
#define NF_   27552     // 2*13776
#define IMG_  128
#define UV_   256
#define NPIX  (IMG_*IMG_)

#define TS_     8                 // tile edge in pixels
#define TPB_    (IMG_/TS_)        // 16 tiles per row/col
#define NTILE_  (TPB_*TPB_)       // 256 tiles per batch
#define NBIN_   (B_*NTILE_)       // 1024 bins
#define LIST_CAP (2*1024*1024)    // entries (8 MB); measured need ~1.2M
#define MAXC_   (LIST_CAP/256 + NBIN_)  // hard bound on phase-B chunks

// ---------------------------------------------------------------- projection
__global__ void __launch_bounds__(256) project_k(
    const float* __restrict__ cam, const float* __restrict__ verts,
    float* __restrict__ vp) {
  int idx = blockIdx.x * 256 + threadIdx.x;
  if (idx >= B_ * NV_) return;
  int b = idx / NV_;
  float c0 = cam[b * 3 + 0], c1 = cam[b * 3 + 1], c2 = cam[b * 3 + 2];
  float tz = 500.0f / (64.0f * c0);                  // FLENGTH/(p*cam0), p=64
  const float* src = verts + (size_t)idx * 3;
  float* dst = vp + (size_t)idx * 3;
  dst[0] = c0 * (src[0] + c1);
  dst[1] = c0 * (src[1] + c2);
  dst[2] = src[2] + tz;
}

// ------------------------------------------------------------------- binning
// Backface cull (area_c < -1e-3, bit-safe bound proven in R1) + bbox(+-1px)
// -> range of overlapped 8x8 tiles. Also outputs z16 = top 16 bits of the
// face's exact zmin (truncation toward zero == downward for positive z, so
// decode(z16) <= zmin: conservative for the hi-z prune).
__device__ __forceinline__ int face_tiles(
    const float* __restrict__ vp, const int* __restrict__ faces, int b, int f,
    int& tx0, int& tx1, int& ty0, int& ty1, unsigned& z16) {
  int ia = faces[f * 3 + 0], ib = faces[f * 3 + 1], ic = faces[f * 3 + 2];
  const float* vb = vp + (size_t)b * NV_ * 3;
  float x0 = vb[ia * 3 + 0], y0 = vb[ia * 3 + 1];
  float x1 = vb[ib * 3 + 0], y1 = vb[ib * 3 + 1];
  float x2 = vb[ic * 3 + 0], y2 = vb[ic * 3 + 1];
  float area_c = (x1 - x0) * (y2 - y0) - (y1 - y0) * (x2 - x0);
  if (area_c < -1e-3f) return 0;
  float xmn = fminf(x0, fminf(x1, x2)), xmx = fmaxf(x0, fmaxf(x1, x2));
  float ymn = fminf(y0, fminf(y1, y2)), ymx = fmaxf(y0, fmaxf(y1, y2));
  int jlo = (int)floorf((xmn + 1.0f) * 64.0f - 0.5f) - 1;
  int jhi = (int)ceilf ((xmx + 1.0f) * 64.0f - 0.5f) + 1;
  int ilo = (int)floorf((1.0f - ymx) * 64.0f - 0.5f) - 1;
  int ihi = (int)ceilf ((1.0f - ymn) * 64.0f - 0.5f) + 1;
  if (jhi < 0 || ihi < 0 || jlo > IMG_ - 1 || ilo > IMG_ - 1) return 0;
  jlo = max(jlo, 0); ilo = max(ilo, 0);
  jhi = min(jhi, IMG_ - 1); ihi = min(ihi, IMG_ - 1);
  tx0 = jlo >> 3; tx1 = jhi >> 3; ty0 = ilo >> 3; ty1 = ihi >> 3;
  float z0 = vb[ia * 3 + 2], z1 = vb[ib * 3 + 2], z2 = vb[ic * 3 + 2];
  z16 = __float_as_uint(fminf(z0, fminf(z1, z2))) >> 16;
  return 1;
}

// Block-local LDS count aggregation (R5-validated). rects carries z16 in the
// high half (0xFFFF = invalid; real z16 ~ 0x40C0..0x4140).
__global__ void __launch_bounds__(256) bin_count_k(
    const float* __restrict__ vp, const int* __restrict__ faces,
    int* __restrict__ cnt, int* __restrict__ rects) {
  __shared__ int scnt[NTILE_];
  int f = blockIdx.x * 256 + threadIdx.x;
  int b = blockIdx.y;
  scnt[threadIdx.x] = 0;
  __syncthreads();
  int tx0, tx1, ty0, ty1;
  unsigned z16 = 0;
  int valid =
      (f < NF_) ? face_tiles(vp, faces, b, f, tx0, tx1, ty0, ty1, z16) : 0;
  if (f < NF_)
    rects[(size_t)b * NF_ + f] =
        valid ? (int)((z16 << 16) | (unsigned)(tx0 | (tx1 << 4) | (ty0 << 8) |
                                               (ty1 << 12)))
              : (int)0xFFFF0000u;
  if (valid)
    for (int ty = ty0; ty <= ty1; ++ty)
      for (int tx = tx0; tx <= tx1; ++tx)
        atomicAdd(&scnt[ty * TPB_ + tx], 1);
  __syncthreads();
  int t = threadIdx.x;
  int v = scnt[t];
  if (v > 0) atomicAdd(&cnt[b * NTILE_ + t], v);
}

// Scan bin counts -> offsets; also build the phase-B work list: chunks of
// 256 faces BEYOND the first 256 (phase A covers those), balanced flat.
__global__ void __launch_bounds__(1024) scan_k(
    const int* __restrict__ cnt, int* __restrict__ off, int* __restrict__ cur,
    int* __restrict__ work, int* __restrict__ nC) {
  __shared__ int sm[NBIN_];
  int t = threadIdx.x;
  int v = cnt[t];
  sm[t] = v;
  __syncthreads();
  for (int d = 1; d < NBIN_; d <<= 1) {
    int u = (t >= d) ? sm[t - d] : 0;
    __syncthreads();
    sm[t] += u;
    __syncthreads();
  }
  int o = sm[t] - v;
  off[t] = o;
  cur[t] = o;
  int nch = (max(v - 256, 0) + 255) >> 8;   // chunks 1..: faces 256..v
  __syncthreads();
  sm[t] = nch;
  __syncthreads();
  for (int d = 1; d < NBIN_; d <<= 1) {
    int u = (t >= d) ? sm[t - d] : 0;
    __syncthreads();
    sm[t] += u;
    __syncthreads();
  }
  int cb = sm[t] - nch;
  if (t == NBIN_ - 1) nC[0] = sm[t];
  for (int c = 0; c < nch; ++c) work[cb + c] = t | ((c + 1) << 10);
}

// Block-local fill (R5-validated). List entry packs (z16 << 15) | fid:
// fid < 27552 fits 15 bits; z16 top bit is 0 (z positive) -> int-safe.
__global__ void __launch_bounds__(256) bin_fill_k(
    const int* __restrict__ rects, int* __restrict__ cur,
    int* __restrict__ list) {
  __shared__ int scnt[NTILE_];
  __shared__ int sbase[NTILE_];
  int f = blockIdx.x * 256 + threadIdx.x;
  int b = blockIdx.y;
  scnt[threadIdx.x] = 0;
  __syncthreads();
  unsigned rv =
      (f < NF_) ? (unsigned)rects[(size_t)b * NF_ + f] : 0xFFFF0000u;
  unsigned hi = rv >> 16;
  int valid = (hi != 0xFFFFu);
  int tx0 = rv & 15, tx1 = (rv >> 4) & 15;
  int ty0 = (rv >> 8) & 15, ty1 = (rv >> 12) & 15;
  if (valid)
    for (int ty = ty0; ty <= ty1; ++ty)
      for (int tx = tx0; tx <= tx1; ++tx)
        atomicAdd(&scnt[ty * TPB_ + tx], 1);
  __syncthreads();
  int t = threadIdx.x;
  int v = scnt[t];
  if (v > 0) sbase[t] = atomicAdd(&cur[b * NTILE_ + t], v);
  __syncthreads();
  scnt[t] = 0;            // reuse as per-bin rank counter
  __syncthreads();
  if (valid) {
    int ev = (int)((hi << 15) | (unsigned)f);
    for (int ty = ty0; ty <= ty1; ++ty)
      for (int tx = tx0; tx <= tx1; ++tx) {
        int bin = ty * TPB_ + tx;
        int r = atomicAdd(&scnt[bin], 1);
        int slot = sbase[bin] + r;
        if (slot < LIST_CAP) list[slot] = ev;
      }
  }
}

// ---------------------------------------------------------------- rasterizer
// Shared inner pass (R6/R2/R3-validated margins). Processes nsurv staged
// faces for this wave's 64 pixels: branchless approx zpa (rel err <~2e-5,
// positive sums, v_rcp ~1ulp); faces not provably above min(win,kbz)*1.001
// (or inside the window-uncertainty bands) go to qmask; the exact reference
// divide chain runs only for qmask survivors after a re-check. Any face
// skipped has reference-exact zp strictly above an exact candidate (kb here
// or the seed already in zkey), so the winning key is bit-identical.
__device__ __forceinline__ void raster_slice(
    const float4 (*F)[64], int nsurv, float px, float py,
    unsigned long long& kb, unsigned& kbz_u) {
  unsigned win_u = 0x7F800000u;
  unsigned long long qm = 0ull;
  for (int q = 0; q < nsurv; ++q) {
    float4 A = F[0][q];
    float4 Bv = F[1][q];
    float4 Cv = F[2][q];
    float w0 = A.x * (py - A.w) - A.y * (px - A.z);
    float w1 = Bv.x * (py - Bv.w) - Bv.y * (px - Bv.z);
    float w2 = Cv.x * (py - Cv.w) - Cv.y * (px - Cv.z);
    float area = (w0 + w1) + w2;
    float mn = fminf(w0, fminf(w1, w2));
    bool pred = (area > 0.0f) && !(mn < 0.0f);
    if (!__any(pred)) continue;
    float4 P = F[4][q];
    float num = (w0 * P.x + w1 * P.y) + w2 * P.z;
    float zpa = (area * P.w) * __builtin_amdgcn_rcpf(num);
    unsigned cu = win_u < kbz_u ? win_u : kbz_u;
    float thrq = __uint_as_float(cu) * 1.001f;
    bool amb = pred && (!(zpa > thrq) ||
                        (zpa > 0.09989f && zpa < 0.10011f) ||
                        (zpa > 24.9724f && zpa < 25.0276f));
    if (amb) qm |= 1ull << q;
    bool ok = pred && (zpa > 0.1001f) && (zpa < 24.975f);
    unsigned zb = __float_as_uint(zpa);
    if (ok && zb < win_u) win_u = zb;
  }
  while (__any(qm != 0ull)) {
    if (qm != 0ull) {
      int q = __ffsll(qm) - 1;
      qm &= qm - 1ull;
      float4 A = F[0][q];
      float4 Bv = F[1][q];
      float4 Cv = F[2][q];
      float w0 = A.x * (py - A.w) - A.y * (px - A.z);
      float w1 = Bv.x * (py - Bv.w) - Bv.y * (px - Bv.z);
      float w2 = Cv.x * (py - Cv.w) - Cv.y * (px - Cv.z);
      float area = (w0 + w1) + w2;
      float4 P = F[4][q];
      float num = (w0 * P.x + w1 * P.y) + w2 * P.z;
      float zpa = (area * P.w) * __builtin_amdgcn_rcpf(num);
      unsigned cu = win_u < kbz_u ? win_u : kbz_u;
      float thrf = __uint_as_float(cu) * 1.001f;
      if (!(zpa > thrf) ||
          (zpa > 0.09989f && zpa < 0.10011f) ||
          (zpa > 24.9724f && zpa < 25.0276f)) {
        float4 Z = F[3][q];
        float b0 = w0 / area, b1 = w1 / area, b2 = w2 / area;
        float invz = (b0 / Z.x + b1 / Z.y) + b2 / Z.z;
        float zp = 1.0f / (invz == 0.0f ? 1.0f : invz);
        if (zp > 0.1f && zp < 25.0f) {
          unsigned long long key =
              ((unsigned long long)__float_as_uint(zp) << 32) |
              (unsigned int)__float_as_int(Z.w);
          if (key < kb) {
            kb = key;
            kbz_u = (unsigned)(kb >> 32);
          }
        }
      }
    }
  }
}

__device__ __forceinline__ void stage_face(
    float4 (*F)[64], const float* __restrict__ vb,
    const int* __restrict__ faces, int fid, int rank) {
  int ia = faces[fid * 3 + 0], ib = faces[fid * 3 + 1], ic = faces[fid * 3 + 2];
  float X0 = vb[ia * 3 + 0], Y0 = vb[ia * 3 + 1], Z0 = vb[ia * 3 + 2];
  float X1 = vb[ib * 3 + 0], Y1 = vb[ib * 3 + 1], Z1 = vb[ib * 3 + 2];
  float X2 = vb[ic * 3 + 0], Y2 = vb[ic * 3 + 1], Z2 = vb[ic * 3 + 2];
  F[0][rank] = make_float4(X2 - X1, Y2 - Y1, X1, Y1);   // d21, v1
  F[1][rank] = make_float4(X0 - X2, Y0 - Y2, X2, Y2);   // d02, v2
  F[2][rank] = make_float4(X1 - X0, Y1 - Y0, X0, Y0);   // d10, v0
  F[3][rank] = make_float4(Z0, Z1, Z2, __int_as_float(fid));
  F[4][rank] = make_float4(Z1 * Z2, Z0 * Z2, Z0 * Z1, Z0 * Z1 * Z2);
}

// Phase A: one block per bin, FIRST 256 faces only (balanced by construction:
// every block does <= 4 wave-slices). Plain store (single writer per pixel)
// doubles as z-buffer init; ~0ull = empty sentinel for shade_k.
__global__ void __launch_bounds__(256) raster_seed_k(
    const float* __restrict__ vp, const int* __restrict__ faces,
    const int* __restrict__ list, const int* __restrict__ cnt,
    const int* __restrict__ off, unsigned long long* __restrict__ zkey) {
  __shared__ float4 fd[4][5][64];
  __shared__ unsigned long long mg[4][64];
  int bin = blockIdx.x;
  int b = bin >> 8;
  int t = bin & 255;
  int tyT = t >> 4, txT = t & 15;
  int ws = threadIdx.x >> 6, lane = threadIdx.x & 63;
  int pi = tyT * TS_ + (lane >> 3);
  int pj = txT * TS_ + (lane & 7);
  float px = fmaf((float)pj, 0.015625f, -0.9921875f);
  float py = fmaf((float)pi, -0.015625f, 0.9921875f);

  int n = min(cnt[bin], 256);
  int base = off[bin];
  int seg = ws * 64;
  int mw = min(n - seg, 64);

  unsigned long long kb = ~0ull;
  unsigned kbz_u = 0x7F800000u;
  if (mw > 0) {
    if (lane < mw) {
      int fid = (int)((unsigned)list[base + seg + lane] & 0x7FFFu);
      stage_face(fd[ws], vp + (size_t)b * NV_ * 3, faces, fid, lane);
    }
    // wave-private LDS slice: per-wave in-order DS pipe, no barrier needed
    raster_slice(fd[ws], mw, px, py, kb, kbz_u);
  }

  mg[ws][lane] = kb;
  __syncthreads();
  if (ws == 0) {
    unsigned long long k0 = mg[0][lane];
    unsigned long long k1 = mg[1][lane];
    unsigned long long k2 = mg[2][lane];
    unsigned long long k3 = mg[3][lane];
    k0 = k1 < k0 ? k1 : k0;
    k2 = k3 < k2 ? k3 : k2;
    k0 = k2 < k0 ? k2 : k0;
    zkey[(size_t)b * NPIX + pi * IMG_ + pj] = k0;
  }
}

// Phase B: balanced chunk grid over faces 256.. of each bin, seeded from the
// phase-A z-buffer (kernel boundary guarantees convergence). Hi-z prefilter:
// one int compare per list entry vs thr_code = top16(wavemax(seed)*1.01);
// skip => exact zp > per-pixel seed z strictly (truncation <2^-7 rel and
// harmonic-interp fp error ~1e-6 both inside the 1% margin), and the seed is
// an exact candidate already in zkey -> bit-identical result. Survivors are
// ballot-compacted and run the validated slice pass; atomicMin merges.
__global__ void __launch_bounds__(256) raster_k(
    const float* __restrict__ vp, const int* __restrict__ faces,
    const int* __restrict__ list, const int* __restrict__ cnt,
    const int* __restrict__ off, const int* __restrict__ work,
    const int* __restrict__ nC, unsigned long long* __restrict__ zkey) {
  __shared__ float4 fd[4][5][64];
  __shared__ unsigned long long mg[4][64];
  __shared__ unsigned sdz[64];
  int bid = blockIdx.x;
  if (bid >= nC[0]) return;                       // block-uniform exit
  int wkv = work[bid];
  int bin = wkv & (NBIN_ - 1);
  int chunk = wkv >> 10;                          // >= 1
  int b = bin >> 8;
  int t = bin & 255;
  int tyT = t >> 4, txT = t & 15;
  int ws = threadIdx.x >> 6, lane = threadIdx.x & 63;
  int pi = tyT * TS_ + (lane >> 3);
  int pj = txT * TS_ + (lane & 7);
  float px = fmaf((float)pj, 0.015625f, -0.9921875f);
  float py = fmaf((float)pi, -0.015625f, 0.9921875f);

  // coherent seed snapshot (no-op RMW; zkey only decreases -> prune exact)
  if (threadIdx.x < 64) {
    unsigned long long s = atomicMin(
        zkey + (size_t)b * NPIX + (tyT * TS_ + (threadIdx.x >> 3)) * IMG_ +
            txT * TS_ + (threadIdx.x & 7),
        ~0ull);
    sdz[threadIdx.x] = (unsigned)(s >> 32);
  }
  __syncthreads();

  unsigned seed_u = min(sdz[lane], 0x7F800000u);  // NaN/empty -> +inf
  unsigned mx = seed_u;
  for (int j = 1; j < 64; j <<= 1) {
    unsigned o = (unsigned)__shfl_xor((int)mx, j, 64);
    mx = o > mx ? o : mx;
  }
  unsigned thr_code = __float_as_uint(__uint_as_float(mx) * 1.01f) >> 16;
  // mx = inf -> thr_code 0x7F80 > any real z16 (~0x4100): prune disabled.

  int n = cnt[bin];
  int seg = (chunk << 8) + (ws << 6);
  int base0 = off[bin] + seg;
  int mw = min(n - seg, 64);
  mw = max(mw, 0);

  bool live = false;
  int fid = 0;
  if (lane < mw) {
    unsigned e = (unsigned)list[base0 + lane];
    live = ((e >> 15) <= thr_code);
    fid = (int)(e & 0x7FFFu);
  }
  unsigned long long bal = __ballot(live);
  unsigned long long kb = ~0ull;
  unsigned kbz_u = seed_u;          // exact candidate z already in zkey
  if (bal != 0ull) {
    int nsurv = (int)__popcll(bal);
    int rank = (int)__popcll(bal & ((1ull << lane) - 1ull));
    if (live)
      stage_face(fd[ws], vp + (size_t)b * NV_ * 3, faces, fid, rank);
    raster_slice(fd[ws], nsurv, px, py, kb, kbz_u);
  }

  mg[ws][lane] = kb;
  __syncthreads();
  if (ws == 0) {
    unsigned long long k0 = mg[0][lane];
    unsigned long long k1 = mg[1][lane];
    unsigned long long k2 = mg[2][lane];
    unsigned long long k3 = mg[3][lane];
    k0 = k1 < k0 ? k1 : k0;
    k2 = k3 < k2 ? k3 : k2;
    k0 = k2 < k0 ? k2 : k0;
    if (k0 != ~0ull)
      atomicMin(zkey + (size_t)b * NPIX + pi * IMG_ + pj, k0);
  }
}

// ------------------------------------------------------------------- shading
#define TAP(ty, tx, wexpr)                                                   \
  {                                                                          \
    int ty_ = (ty), tx_ = (tx);                                              \
    float w_ = (wexpr);                                                      \
    float valid_ =                                                           \
        (tx_ >= 0 && tx_ < UV_ && ty_ >= 0 && ty_ < UV_) ? 1.0f : 0.0f;      \
    float wv_ = w_ * valid_;                                                 \
    int cy_ = min(max(ty_, 0), UV_ - 1), cx_ = min(max(tx_, 0), UV_ - 1);    \
    int o_ = cy_ * UV_ + cx_;                                                \
    cr = cr + img[o_] * wv_;                                                 \
    cg = cg + img[UV_ * UV_ + o_] * wv_;                                     \
    cb = cb + img[2 * UV_ * UV_ + o_] * wv_;                                 \
  }

__global__ void __launch_bounds__(256) shade_k(
    const float* __restrict__ vp, const int* __restrict__ faces,
    const float* __restrict__ uv, const float* __restrict__ samp,
    const unsigned long long* __restrict__ zkey, float* __restrict__ out) {
  int idx = blockIdx.x * 256 + threadIdx.x;
  if (idx >= B_ * NPIX) return;
  int b = idx / NPIX;
  int p = idx - b * NPIX;
  int ii = p / IMG_;
  int jj = p - ii * IMG_;

  unsigned long long key = zkey[idx];
  float cr = 0.0f, cg = 0.0f, cb = 0.0f;
  if (key != 0xFFFFFFFFFFFFFFFFull) {
    int f = (int)(key & 0xFFFFFFFFull);
    int ia = faces[f * 3 + 0], ib = faces[f * 3 + 1], ic = faces[f * 3 + 2];
    const float* vb = vp + (size_t)b * NV_ * 3;
    float x0 = vb[ia * 3 + 0], y0 = vb[ia * 3 + 1];
    float x1 = vb[ib * 3 + 0], y1 = vb[ib * 3 + 1];
    float x2 = vb[ic * 3 + 0], y2 = vb[ic * 3 + 1];
    float px = (float)(2 * jj + 1) / 128.0f - 1.0f;
    float py = 1.0f - (float)(2 * ii + 1) / 128.0f;
    float w0 = (x2 - x1) * (py - y1) - (y2 - y1) * (px - x1);
    float w1 = (x0 - x2) * (py - y2) - (y0 - y2) * (px - x2);
    float w2 = (x1 - x0) * (py - y0) - (y1 - y0) * (px - x0);
    float area = (w0 + w1) + w2;
    float s = (area == 0.0f) ? 1.0f : area;
    float b0 = w0 / s, b1 = w1 / s;
    int t0 = min(max((int)floorf(b0 * 3.0f), 0), 2);
    int t1 = min(max((int)floorf(b1 * 3.0f), 0), 2);

    // lazy texture fetch: textures[b,f,t0,t1,*,c] == bilinear(uv_imgs[b],
    // sampler[f, t0*3+t1]); lighting multiplier is exactly 1.0 -> skipped.
    const float* g = samp + ((size_t)f * 9 + (size_t)(t0 * 3 + t1)) * 2;
    float gx = g[0], gy = g[1];
    float x = (gx + 1.0f) * 128.0f - 0.5f;   // (g+1)*(W*0.5)-0.5, W=256
    float y = (gy + 1.0f) * 128.0f - 0.5f;
    float x0f = floorf(x), y0f = floorf(y);
    float wx = x - x0f, wy = y - y0f;
    int xi = (int)x0f, yi = (int)y0f;
    float omwx = 1.0f - wx, omwy = 1.0f - wy;
    const float* img = uv + (size_t)b * 3 * UV_ * UV_;
    // reference accumulation order: (y0,x0)+(y0,x0+1)+(y0+1,x0)+(y0+1,x0+1)
    TAP(yi,     xi,     omwx * omwy)
    TAP(yi,     xi + 1, wx * omwy)
    TAP(yi + 1, xi,     omwx * wy)
    TAP(yi + 1, xi + 1, wx * wy)
  }
  out[((size_t)b * 3 + 0) * NPIX + p] = cr;
  out[((size_t)b * 3 + 1) * NPIX + p] = cg;
  out[((size_t)b * 3 + 2) * NPIX + p] = cb;
}

// ------------------------------------------------------------------- launch
extern "C" void kernel_launch(void* const* d_in, const int* in_sizes, int n_in,
                              void* d_out, int out_size, void* d_ws,
                              size_t ws_size, hipStream_t stream) {
  const float* cam   = (const float*)d_in[0];
  const float* verts = (const float*)d_in[1];
  const float* uv    = (const float*)d_in[2];
  const float* samp  = (const float*)d_in[3];
  const int*   faces = (const int*)d_in[4];

  char* ws = (char*)d_ws;
  size_t o = 0;
  unsigned long long* zkey = (unsigned long long*)(ws + o);
  o += (size_t)B_ * NPIX * 8;                                   // 512 KB
  float* vp = (float*)(ws + o);
  o += ((size_t)B_ * NV_ * 3 * 4 + 1023) & ~1023ull;            // ~331 KB
  int* cnt   = (int*)(ws + o); o += NBIN_ * 4;
  int* offs  = (int*)(ws + o); o += NBIN_ * 4;
  int* cur   = (int*)(ws + o); o += NBIN_ * 4;
  int* nC    = (int*)(ws + o); o += 1024;
  int* work  = (int*)(ws + o); o += (size_t)MAXC_ * 4;          // 36 KB
  int* rects = (int*)(ws + o); o += (size_t)B_ * NF_ * 4;       // 440 KB
  int* list  = (int*)(ws + o);                                  // 8 MB

  hipMemsetAsync(cnt, 0, NBIN_ * 4, stream);
  project_k<<<(B_ * NV_ + 255) / 256, 256, 0, stream>>>(cam, verts, vp);
  dim3 bgrid((NF_ + 255) / 256, B_);
  bin_count_k<<<bgrid, 256, 0, stream>>>(vp, faces, cnt, rects);
  scan_k<<<1, NBIN_, 0, stream>>>(cnt, offs, cur, work, nC);
  bin_fill_k<<<bgrid, 256, 0, stream>>>(rects, cur, list);
  raster_seed_k<<<NBIN_, 256, 0, stream>>>(vp, faces, list, cnt, offs, zkey);
  raster_k<<<MAXC_, 256, 0, stream>>>(vp, faces, list, cnt, offs, work, nC,
                                      zkey);
  shade_k<<<(B_ * NPIX + 255) / 256, 256, 0, stream>>>(vp, faces, uv, samp,
                                                       zkey, (float*)d_out);
}